// Round 2
// baseline (490.094 us; speedup 1.0000x reference)
//
#include <hip/hip_runtime.h>

#define BATCH 32
#define CDIM 256
#define HW 1024            // 32*32
#define NROWS 32768        // BATCH*HW
#define KCODES 1024
#define ZQ_ELEMS 8388608   // 32*256*1024
#define IDX_OFF ZQ_ELEMS
#define LOSS_OFF (ZQ_ELEMS + NROWS)

// ---- numpy-bit-exact pairwise sum of squares over 256 contiguous floats ----
__device__ __forceinline__ float np_sumsq_256(const float* __restrict__ a) {
    float half[2];
#pragma unroll
    for (int h = 0; h < 2; ++h) {
        const float* p = a + h * 128;
        float r[8];
#pragma unroll
        for (int j = 0; j < 8; ++j) r[j] = __fmul_rn(p[j], p[j]);
#pragma unroll
        for (int i = 8; i < 128; i += 8) {
#pragma unroll
            for (int j = 0; j < 8; ++j)
                r[j] = __fadd_rn(r[j], __fmul_rn(p[i + j], p[i + j]));
        }
        float ta = __fadd_rn(__fadd_rn(r[0], r[1]), __fadd_rn(r[2], r[3]));
        float tb = __fadd_rn(__fadd_rn(r[4], r[5]), __fadd_rn(r[6], r[7]));
        half[h] = __fadd_rn(ta, tb);
    }
    return __fadd_rn(half[0], half[1]);
}

// ---- kernel 1: e2[k] = np-exact sum(emb[k,:]**2) ----
__global__ void __launch_bounds__(256)
e2_kernel(const float* __restrict__ emb, float* __restrict__ e2) {
    int k = blockIdx.x * blockDim.x + threadIdx.x;
    if (k >= KCODES) return;
    e2[k] = np_sumsq_256(emb + (size_t)k * CDIM);
}

// ---- kernel 2: fused distance + argmin ----
// Block: 256 threads, 32 rows x 1024 codes.
// Wave layout: kx = lane&7 (code groups), my = lane>>3 (row groups) so both
// z and e LDS reads are 8-distinct-address broadcasts (conflict-free:
// z stride 260 -> banks 4*my%32; e stride 20 -> banks 20*kx%32).
// Thread tile: 4 rows (my+8i) x 8 codes (kgroup+32j), kgroup = wave*8+kx.
// K chunks of 256 codes (4 chunks), C chunks of 16 (stage index u = kc*16+cc).
__global__ void __launch_bounds__(256, 3)
argmin_kernel(const float* __restrict__ z, const float* __restrict__ emb,
              const float* __restrict__ e2g, float* __restrict__ out_idx_f,
              int* __restrict__ ws_idx) {
    __shared__ __align__(16) float z_lds[32 * 260];   // 33280 B, [m][c] pad to 260
    __shared__ __align__(16) float e_lds[256 * 20];   // 20480 B, [k][16c] pad to 20
    __shared__ float z2_lds[32];

    const int t    = threadIdx.x;
    const int lane = t & 63;
    const int wave = t >> 6;
    const int kx   = lane & 7;
    const int my   = lane >> 3;          // 0..7
    const int kgroup = wave * 8 + kx;    // 0..31

    const int n0  = blockIdx.x * 32;
    const int b   = n0 >> 10;
    const int hw0 = n0 & 1023;
    const float* zbase = z + (size_t)b * (CDIM * HW) + hw0;

    // stage z tile [32 hw][256 c] -> z_lds[m][c]
#pragma unroll
    for (int p = 0; p < 8; ++p) {
        int id = p * 256 + t;        // 0..2047 float4s
        int c  = id >> 3;            // 0..255
        int m4 = id & 7;
        float4 v = *(const float4*)(zbase + (size_t)c * HW + m4 * 4);
        z_lds[(m4 * 4 + 0) * 260 + c] = v.x;
        z_lds[(m4 * 4 + 1) * 260 + c] = v.y;
        z_lds[(m4 * 4 + 2) * 260 + c] = v.z;
        z_lds[(m4 * 4 + 3) * 260 + c] = v.w;
    }
    __syncthreads();

    if (t < 32) z2_lds[t] = np_sumsq_256(&z_lds[t * 260]);
    __syncthreads();

    float z2r[4];
#pragma unroll
    for (int i = 0; i < 4; ++i) z2r[i] = z2_lds[my + 8 * i];

    float best_s[4];
    int   best_k[4];
#pragma unroll
    for (int i = 0; i < 4; ++i) { best_s[i] = 3.402823466e+38f; best_k[i] = 0; }

    float acc[4][8];
#pragma unroll
    for (int i = 0; i < 4; ++i)
#pragma unroll
        for (int j = 0; j < 8; ++j) acc[i][j] = 0.f;

    // staging addresses: thread stages 4 float4s per chunk:
    // kl = (t>>2) + 64p, c4 = t&3
    const int kl_base = t >> 2;
    const int c4      = t & 3;

    // prefetch u = 0
    float4 pv[4];
#pragma unroll
    for (int p = 0; p < 4; ++p)
        pv[p] = *(const float4*)&emb[(size_t)(kl_base + 64 * p) * CDIM + c4 * 4];

    for (int u = 0; u < 64; ++u) {
        const int kc = u >> 4;
        const int cc = u & 15;
        const int c0 = cc * 16;

        __syncthreads();   // previous s-loop readers done
#pragma unroll
        for (int p = 0; p < 4; ++p)
            *(float4*)&e_lds[(kl_base + 64 * p) * 20 + c4 * 4] = pv[p];

        if (u < 63) {
            const int un = u + 1;
            const int kcn = un >> 4, ccn = un & 15;
#pragma unroll
            for (int p = 0; p < 4; ++p)
                pv[p] = *(const float4*)&emb[(size_t)(kcn * 256 + kl_base + 64 * p) * CDIM
                                             + ccn * 16 + c4 * 4];
        }
        __syncthreads();

#pragma unroll
        for (int s = 0; s < 4; ++s) {
            float4 zf[4], ef[8];
#pragma unroll
            for (int i = 0; i < 4; ++i)
                zf[i] = *(const float4*)&z_lds[(my + 8 * i) * 260 + c0 + s * 4];
#pragma unroll
            for (int j = 0; j < 8; ++j)
                ef[j] = *(const float4*)&e_lds[(kgroup + 32 * j) * 20 + s * 4];
#pragma unroll
            for (int i = 0; i < 4; ++i)
#pragma unroll
                for (int j = 0; j < 8; ++j) {
                    acc[i][j] = fmaf(zf[i].x, ef[j].x, acc[i][j]);
                    acc[i][j] = fmaf(zf[i].y, ef[j].y, acc[i][j]);
                    acc[i][j] = fmaf(zf[i].z, ef[j].z, acc[i][j]);
                    acc[i][j] = fmaf(zf[i].w, ef[j].w, acc[i][j]);
                }
        }

        if (cc == 15) {
            // epilogue for kc: d = fl(fl(z2+e2) - 2*dot); ascending k in j
            const int k0 = kc * 256;
#pragma unroll
            for (int j = 0; j < 8; ++j) {
                const int kk = k0 + kgroup + 32 * j;
                const float e2k = e2g[kk];
#pragma unroll
                for (int i = 0; i < 4; ++i) {
                    float t1 = __fadd_rn(z2r[i], e2k);
                    float d  = __fsub_rn(t1, acc[i][j] + acc[i][j]);
                    if (d < best_s[i]) { best_s[i] = d; best_k[i] = kk; }
                    acc[i][j] = 0.f;
                }
            }
        }
    }

    // cross-thread reduce: per row m, 32 candidates (one per kgroup)
    __syncthreads();
    float* red_s = e_lds;                  // 1024 floats
    int*   red_k = (int*)(e_lds + 1024);   // 1024 ints
#pragma unroll
    for (int i = 0; i < 4; ++i) {
        int m = my + 8 * i;
        red_s[m * 32 + kgroup] = best_s[i];
        red_k[m * 32 + kgroup] = best_k[i];
    }
    __syncthreads();
    if (t < 32) {
        float bs = 3.402823466e+38f;
        int bk = KCODES;
        for (int x2 = 0; x2 < 32; ++x2) {
            float s = red_s[t * 32 + x2];
            int  k2 = red_k[t * 32 + x2];
            if (s < bs || (s == bs && k2 < bk)) { bs = s; bk = k2; }
        }
        out_idx_f[n0 + t] = (float)bk;
        ws_idx[n0 + t] = bk;
    }
}

// ---- kernel 3: gather z_q, write z_q_st = z + (z_q - z), partial loss sums ----
// grid 256 = 32 b x 8 c-groups of 32 c; thread owns 4 consecutive hw.
__global__ void __launch_bounds__(256)
gather_kernel(const float* __restrict__ z, const float* __restrict__ emb,
              const int* __restrict__ ws_idx, float* __restrict__ out_zq,
              float* __restrict__ partials) {
    const int t  = threadIdx.x;
    const int b  = blockIdx.x >> 3;
    const int cg = blockIdx.x & 7;
    const int hw4 = t * 4;

    const int4 iv = *(const int4*)&ws_idx[b * HW + hw4];
    const float* zb = z + (size_t)b * (CDIM * HW) + hw4;
    float* ob = out_zq + (size_t)b * (CDIM * HW) + hw4;
    const float* e0p = emb + (size_t)iv.x * CDIM;
    const float* e1p = emb + (size_t)iv.y * CDIM;
    const float* e2p = emb + (size_t)iv.z * CDIM;
    const float* e3p = emb + (size_t)iv.w * CDIM;

    float lsum = 0.f;
#pragma unroll 4
    for (int c = cg * 32; c < cg * 32 + 32; ++c) {
        float4 zv = *(const float4*)&zb[(size_t)c * HW];
        float d0 = e0p[c] - zv.x;
        float d1 = e1p[c] - zv.y;
        float d2 = e2p[c] - zv.z;
        float d3 = e3p[c] - zv.w;
        float4 ov = { zv.x + d0, zv.y + d1, zv.z + d2, zv.w + d3 };
        *(float4*)&ob[(size_t)c * HW] = ov;
        lsum = fmaf(d0, d0, lsum);
        lsum = fmaf(d1, d1, lsum);
        lsum = fmaf(d2, d2, lsum);
        lsum = fmaf(d3, d3, lsum);
    }
#pragma unroll
    for (int off = 32; off > 0; off >>= 1) lsum += __shfl_down(lsum, off);
    __shared__ float wsum[4];
    if ((t & 63) == 0) wsum[t >> 6] = lsum;
    __syncthreads();
    if (t == 0) partials[blockIdx.x] = (wsum[0] + wsum[1]) + (wsum[2] + wsum[3]);
}

// ---- kernel 4: finalize loss = 1.25 * mean(diff^2) ----
__global__ void loss_kernel(const float* __restrict__ partials, float* __restrict__ out_loss) {
    const int t = threadIdx.x;
    float v = partials[t];
#pragma unroll
    for (int off = 32; off > 0; off >>= 1) v += __shfl_down(v, off);
    __shared__ float wsum[4];
    if ((t & 63) == 0) wsum[t >> 6] = v;
    __syncthreads();
    if (t == 0) {
        float total = (wsum[0] + wsum[1]) + (wsum[2] + wsum[3]);
        out_loss[0] = 1.25f * total / 8388608.0f;
    }
}

extern "C" void kernel_launch(void* const* d_in, const int* in_sizes, int n_in,
                              void* d_out, int out_size, void* d_ws, size_t ws_size,
                              hipStream_t stream) {
    const float* z   = (const float*)d_in[0];
    const float* emb = (const float*)d_in[1];
    float* out = (float*)d_out;

    float* e2       = (float*)d_ws;                                   // 1024 f
    int*   ws_idx   = (int*)((char*)d_ws + 4096);                     // 32768 i32
    float* partials = (float*)((char*)d_ws + 4096 + 131072);          // 256 f

    hipLaunchKernelGGL(e2_kernel, dim3(4), dim3(256), 0, stream, emb, e2);
    hipLaunchKernelGGL(argmin_kernel, dim3(1024), dim3(256), 0, stream,
                       z, emb, e2, out + IDX_OFF, ws_idx);
    hipLaunchKernelGGL(gather_kernel, dim3(256), dim3(256), 0, stream,
                       z, emb, ws_idx, out, partials);
    hipLaunchKernelGGL(loss_kernel, dim3(1), dim3(256), 0, stream,
                       partials, out + LOSS_OFF);
}